// Round 1
// baseline (5324.218 us; speedup 1.0000x reference)
//
#include <hip/hip_runtime.h>
#include <math.h>

#define N_NODES 20000
#define N_EDGES 1280000
#define HDIM 64
#define NLAYERS 4

__device__ __forceinline__ float silu_f(float x) {
    return x / (1.0f + __expf(-x));
}

// ---------------- init: h = |vel| * emb_w + emb_b; coord/vel unpack ----------------
__global__ void k_init(const float* __restrict__ inp,
                       const float* __restrict__ emb_w,
                       const float* __restrict__ emb_b,
                       float* __restrict__ h,
                       float* __restrict__ coord,
                       float* __restrict__ vel) {
    int t = blockIdx.x * blockDim.x + threadIdx.x;   // n*64+f
    int n = t >> 6, f = t & 63;
    if (n >= N_NODES) return;
    float vx = inp[n*6+3], vy = inp[n*6+4], vz = inp[n*6+5];
    float sp = sqrtf(vx*vx + vy*vy + vz*vz);
    h[t] = sp * emb_w[f] + emb_b[f];
    if (f < 3) {
        coord[n*3+f] = inp[n*6+f];
        vel[n*3+f]   = inp[n*6+3+f];
    }
}

__global__ void k_count(const int* __restrict__ recv, float* __restrict__ cnt) {
    int t = blockIdx.x*blockDim.x + threadIdx.x;
    if (t < N_EDGES) atomicAdd(&cnt[recv[t]], 1.0f);
}

__global__ void k_invert(float* __restrict__ cnt) {
    int t = blockIdx.x*blockDim.x + threadIdx.x;
    if (t < N_NODES) cnt[t] = 1.0f / fmaxf(cnt[t], 1.0f);
}

// ---------------- fused edge kernel (per layer) ----------------
// Block = 256 threads, 64 edges/block. Grid = E/64 = 20000.
// Thread (eg=tid&15, fg=tid>>4) owns edges {eg,eg+16,eg+32,eg+48} x feats {4fg..4fg+3}.
__launch_bounds__(256, 2)
__global__ void k_edge(const int* __restrict__ send, const int* __restrict__ recv,
                       const float* __restrict__ h, const float* __restrict__ coord,
                       const float* __restrict__ W1, const float* __restrict__ b1,
                       const float* __restrict__ W2, const float* __restrict__ b2,
                       const float* __restrict__ CW1, const float* __restrict__ cb1,
                       const float* __restrict__ CWo,
                       float* __restrict__ aggs, float* __restrict__ aggm) {
    __shared__ float in_tile[64*128];   // edge-major rows of 128 (h_send|h_recv), swizzled 16B chunks
                                        // later aliased: [0..4095]=t1_tile, [4096..8191]=ef_tile
    __shared__ float w_tile[32*64];     // W1 K-chunks
    __shared__ float w2_tile[64*64];    // W2, then CW1
    __shared__ int   se[64], re[64];
    __shared__ float cdx[64], cdy[64], cdz[64], rad[64], cmacc[64];

    const int tid = threadIdx.x;
    const int eg = tid & 15, fg = tid >> 4;
    const int e7 = eg & 7;
    const int ebase = blockIdx.x * 64;

    // phase 0: indices, coord diff, radial
    if (tid < 64) {
        int s = send[ebase + tid], r = recv[ebase + tid];
        se[tid] = s; re[tid] = r;
        float dx = coord[s*3+0] - coord[r*3+0];
        float dy = coord[s*3+1] - coord[r*3+1];
        float dz = coord[s*3+2] - coord[r*3+2];
        cdx[tid]=dx; cdy[tid]=dy; cdz[tid]=dz;
        rad[tid] = dx*dx+dy*dy+dz*dz;
        cmacc[tid] = 0.0f;
    }
    __syncthreads();

    // stage in_tile: cols 0..63 = h[send], 64..127 = h[recv]; coalesced global reads
    for (int it = 0; it < 32; ++it) {
        int idx = tid + (it << 8);
        int col = idx & 127;
        int e = idx >> 7;
        float v = (col < 64) ? h[se[e]*64 + col] : h[re[e]*64 + (col-64)];
        int sw = (col & 3) | ((((col >> 2) ^ (e & 7)) & 31) << 2);
        in_tile[e*128 + sw] = v;
    }

    // acc init: radial*W1[128][:] + b1
    float acc[4][4];
    {
        const float4 wr = *(const float4*)&W1[128*64 + (fg<<2)];
        const float4 bb = *(const float4*)&b1[fg<<2];
        #pragma unroll
        for (int i = 0; i < 4; ++i) {
            float rv = rad[eg + 16*i];
            acc[i][0] = rv*wr.x + bb.x;
            acc[i][1] = rv*wr.y + bb.y;
            acc[i][2] = rv*wr.z + bb.z;
            acc[i][3] = rv*wr.w + bb.w;
        }
    }

    // GEMM1: K=128 in 4 chunks of 32 rows
    for (int kc = 0; kc < 4; ++kc) {
        __syncthreads();
        for (int it = 0; it < 8; ++it) {
            int idx = tid + (it << 8);
            int kl = idx >> 6, f = idx & 63;
            w_tile[kl*64 + f] = W1[(kc*32 + kl)*64 + f];
        }
        __syncthreads();
        #pragma unroll
        for (int kv = 0; kv < 8; ++kv) {
            const int kvec = (kc<<3) + kv;
            float4 a[4];
            #pragma unroll
            for (int i = 0; i < 4; ++i)
                a[i] = *(const float4*)&in_tile[(eg+16*i)*128 + (((kvec ^ e7) & 31) << 2)];
            #pragma unroll
            for (int kk = 0; kk < 4; ++kk) {
                const float4 b = *(const float4*)&w_tile[((kv<<2)+kk)*64 + (fg<<2)];
                #pragma unroll
                for (int i = 0; i < 4; ++i) {
                    const float* ap = (const float*)&a[i];
                    float av = ap[kk];
                    acc[i][0] += av*b.x; acc[i][1] += av*b.y;
                    acc[i][2] += av*b.z; acc[i][3] += av*b.w;
                }
            }
        }
    }

    __syncthreads();   // in_tile dead; safe to alias
    float* t1_tile = in_tile;          // [64][64] swizzled
    float* ef_tile = in_tile + 4096;   // [64][64] swizzled

    // t1 = silu(acc); stage W2
    #pragma unroll
    for (int i = 0; i < 4; ++i) {
        int e = eg + 16*i;
        float4 v;
        v.x = silu_f(acc[i][0]); v.y = silu_f(acc[i][1]);
        v.z = silu_f(acc[i][2]); v.w = silu_f(acc[i][3]);
        *(float4*)&t1_tile[e*64 + (((fg ^ e7) & 15) << 2)] = v;
    }
    for (int it = 0; it < 16; ++it) {
        int idx = tid + (it << 8);
        w2_tile[idx] = W2[idx];
    }
    __syncthreads();

    // GEMM2: ef = silu(t1 @ W2 + b2), K=64
    {
        const float4 bb = *(const float4*)&b2[fg<<2];
        #pragma unroll
        for (int i=0;i<4;++i){ acc[i][0]=bb.x; acc[i][1]=bb.y; acc[i][2]=bb.z; acc[i][3]=bb.w; }
    }
    #pragma unroll
    for (int kvec = 0; kvec < 16; ++kvec) {
        float4 a[4];
        #pragma unroll
        for (int i = 0; i < 4; ++i)
            a[i] = *(const float4*)&t1_tile[(eg+16*i)*64 + (((kvec ^ e7) & 15) << 2)];
        #pragma unroll
        for (int kk = 0; kk < 4; ++kk) {
            const float4 b = *(const float4*)&w2_tile[((kvec<<2)+kk)*64 + (fg<<2)];
            #pragma unroll
            for (int i = 0; i < 4; ++i) {
                const float* ap = (const float*)&a[i];
                float av = ap[kk];
                acc[i][0] += av*b.x; acc[i][1] += av*b.y;
                acc[i][2] += av*b.z; acc[i][3] += av*b.w;
            }
        }
    }
    #pragma unroll
    for (int i = 0; i < 4; ++i) {
        int e = eg + 16*i;
        float4 v;
        v.x = silu_f(acc[i][0]); v.y = silu_f(acc[i][1]);
        v.z = silu_f(acc[i][2]); v.w = silu_f(acc[i][3]);
        *(float4*)&ef_tile[e*64 + (((fg ^ e7) & 15) << 2)] = v;
    }
    __syncthreads();   // ef complete, W2 reads done -> restage CW1
    for (int it = 0; it < 16; ++it) {
        int idx = tid + (it << 8);
        w2_tile[idx] = CW1[idx];
    }
    __syncthreads();

    // GEMM3: u = silu(ef @ CW1 + cb1); cm = u @ CWo (reduced via LDS atomics)
    {
        const float4 cb = *(const float4*)&cb1[fg<<2];
        #pragma unroll
        for (int i=0;i<4;++i){ acc[i][0]=cb.x; acc[i][1]=cb.y; acc[i][2]=cb.z; acc[i][3]=cb.w; }
    }
    #pragma unroll
    for (int kvec = 0; kvec < 16; ++kvec) {
        float4 a[4];
        #pragma unroll
        for (int i = 0; i < 4; ++i)
            a[i] = *(const float4*)&ef_tile[(eg+16*i)*64 + (((kvec ^ e7) & 15) << 2)];
        #pragma unroll
        for (int kk = 0; kk < 4; ++kk) {
            const float4 b = *(const float4*)&w2_tile[((kvec<<2)+kk)*64 + (fg<<2)];
            #pragma unroll
            for (int i = 0; i < 4; ++i) {
                const float* ap = (const float*)&a[i];
                float av = ap[kk];
                acc[i][0] += av*b.x; acc[i][1] += av*b.y;
                acc[i][2] += av*b.z; acc[i][3] += av*b.w;
            }
        }
    }
    {
        const float4 co = *(const float4*)&CWo[fg<<2];
        #pragma unroll
        for (int i = 0; i < 4; ++i) {
            float p = silu_f(acc[i][0])*co.x + silu_f(acc[i][1])*co.y
                    + silu_f(acc[i][2])*co.z + silu_f(acc[i][3])*co.w;
            atomicAdd(&cmacc[eg + 16*i], p);
        }
    }
    __syncthreads();

    // trans = clip(cd*cm) -> aggmean (scatter)
    if (tid < 64) {
        float cm = cmacc[tid];
        int r3 = re[tid]*3;
        float t0 = fminf(fmaxf(cdx[tid]*cm, -100.f), 100.f);
        float t1 = fminf(fmaxf(cdy[tid]*cm, -100.f), 100.f);
        float t2 = fminf(fmaxf(cdz[tid]*cm, -100.f), 100.f);
        atomicAdd(&aggm[r3+0], t0);
        atomicAdd(&aggm[r3+1], t1);
        atomicAdd(&aggm[r3+2], t2);
    }
    // ef -> aggsum (coalesced per-wave 256B atomic regions)
    for (int it = 0; it < 16; ++it) {
        int idx = tid + (it << 8);
        int f = idx & 63, e = idx >> 6;
        float v = ef_tile[e*64 + ((f & 3) | ((((f >> 2) ^ (e & 7)) & 15) << 2))];
        atomicAdd(&aggs[re[e]*64 + f], v);
    }
}

// ---------------- node kernel (per layer): vel gate + vel/coord update + node MLP ----------------
__launch_bounds__(256, 4)
__global__ void k_node(const float* __restrict__ aggs, const float* __restrict__ aggm,
                       const float* __restrict__ icnt,
                       const float* __restrict__ VW1, const float* __restrict__ vb1,
                       const float* __restrict__ VW2, const float* __restrict__ vb2,
                       const float* __restrict__ NW1, const float* __restrict__ nb1,
                       const float* __restrict__ NW2, const float* __restrict__ nb2,
                       float* __restrict__ h, float* __restrict__ coord,
                       float* __restrict__ vel) {
    __shared__ float hs[4][64], as[4][64], tt[4][64];
    const int tid = threadIdx.x;
    const int nn = tid >> 6, f = tid & 63;     // wave nn handles node n
    const int n = blockIdx.x*4 + nn;
    float hv = h[n*64+f];
    hs[nn][f] = hv;
    as[nn][f] = aggs[n*64+f];
    __syncthreads();

    // velocity gate: v = silu(h@VW1+vb1) @ VW2 + vb2  (wave-local reduce)
    float a1 = vb1[f];
    for (int k = 0; k < 64; ++k) a1 += hs[nn][k] * VW1[k*64+f];
    float p = silu_f(a1) * VW2[f];
    #pragma unroll
    for (int o = 32; o > 0; o >>= 1) p += __shfl_down(p, o);
    float vgate = __shfl(p, 0) + vb2[0];

    if (f < 3) {
        float nv = aggm[n*3+f]*icnt[n] + vgate*vel[n*3+f];
        vel[n*3+f] = nv;
        coord[n*3+f] += nv;
    }

    // node MLP: h = silu([h,agg]@NW1+nb1)@NW2 + nb2 + h
    float b = nb1[f];
    for (int k = 0; k < 64; ++k) b += hs[nn][k]*NW1[k*64+f];
    for (int k = 0; k < 64; ++k) b += as[nn][k]*NW1[(64+k)*64+f];
    __syncthreads();
    tt[nn][f] = silu_f(b);
    __syncthreads();
    float o = nb2[f] + hv;
    for (int k = 0; k < 64; ++k) o += tt[nn][k]*NW2[k*64+f];
    h[n*64+f] = o;
}

__global__ void k_out(const float* __restrict__ coord, const float* __restrict__ vel,
                      float* __restrict__ out) {
    int t = blockIdx.x*blockDim.x + threadIdx.x;
    if (t >= N_NODES*6) return;
    int n = t/6, c = t%6;
    out[t] = (c < 3) ? coord[n*3+c] : vel[n*3+(c-3)];
}

extern "C" void kernel_launch(void* const* d_in, const int* in_sizes, int n_in,
                              void* d_out, int out_size, void* d_ws, size_t ws_size,
                              hipStream_t stream) {
    const float* inp   = (const float*)d_in[0];
    // d_in[1] = node_masks (all ones) -- unused
    const int*   send  = (const int*)d_in[2];
    const int*   recv  = (const int*)d_in[3];
    const float* emb_w = (const float*)d_in[4];
    const float* emb_b = (const float*)d_in[5];
    const float* ew1   = (const float*)d_in[6];
    const float* eb1   = (const float*)d_in[7];
    const float* ew2   = (const float*)d_in[8];
    const float* eb2   = (const float*)d_in[9];
    const float* nw1   = (const float*)d_in[10];
    const float* nb1   = (const float*)d_in[11];
    const float* nw2   = (const float*)d_in[12];
    const float* nb2   = (const float*)d_in[13];
    const float* cw1   = (const float*)d_in[14];
    const float* cb1   = (const float*)d_in[15];
    const float* cwo   = (const float*)d_in[16];
    const float* vw1   = (const float*)d_in[17];
    const float* vb1   = (const float*)d_in[18];
    const float* vw2   = (const float*)d_in[19];
    const float* vb2   = (const float*)d_in[20];

    float* ws    = (float*)d_ws;
    float* h     = ws;                    // N*64
    float* coord = h + N_NODES*64;        // N*3
    float* vel   = coord + N_NODES*3;     // N*3
    float* aggs  = vel + N_NODES*3;       // N*64
    float* aggm  = aggs + N_NODES*64;     // N*3  (contiguous with aggs)
    float* icnt  = aggm + N_NODES*3;      // N

    hipMemsetAsync(icnt, 0, N_NODES*sizeof(float), stream);
    k_init<<<(N_NODES*64)/256, 256, 0, stream>>>(inp, emb_w, emb_b, h, coord, vel);
    k_count<<<(N_EDGES+255)/256, 256, 0, stream>>>(recv, icnt);
    k_invert<<<(N_NODES+255)/256, 256, 0, stream>>>(icnt);

    for (int l = 0; l < NLAYERS; ++l) {
        hipMemsetAsync(aggs, 0, (size_t)N_NODES*67*sizeof(float), stream);
        k_edge<<<N_EDGES/64, 256, 0, stream>>>(send, recv, h, coord,
            ew1 + (size_t)l*129*64, eb1 + l*64,
            ew2 + (size_t)l*64*64,  eb2 + l*64,
            cw1 + (size_t)l*64*64,  cb1 + l*64, cwo + l*64,
            aggs, aggm);
        k_node<<<N_NODES/4, 256, 0, stream>>>(aggs, aggm, icnt,
            vw1 + (size_t)l*64*64, vb1 + l*64, vw2 + l*64, vb2 + l,
            nw1 + (size_t)l*128*64, nb1 + l*64,
            nw2 + (size_t)l*64*64,  nb2 + l*64,
            h, coord, vel);
    }
    k_out<<<(N_NODES*6+255)/256, 256, 0, stream>>>(coord, vel, (float*)d_out);
}

// Round 4
// 2320.884 us; speedup vs baseline: 2.2940x; 2.2940x over previous
//
#include <hip/hip_runtime.h>
#include <math.h>

#define N_NODES 20000
#define N_EDGES 1280000
#define NLAYERS 4
#define TSTRIDE 68   // bf16 elements per LDS tile row (padded 64 -> 68)

typedef short bf16x8 __attribute__((ext_vector_type(8)));
typedef float f32x4  __attribute__((ext_vector_type(4)));
typedef long long i64;
typedef unsigned short us;

__device__ __forceinline__ float silu_f(float x) {
    return x / (1.0f + __expf(-x));
}

// fp32 -> bf16 bits, round-to-nearest-even
__device__ __forceinline__ us f2b(float x) {
    union { float f; unsigned u; } v; v.f = x;
    unsigned r = v.u + 0x7FFF + ((v.u >> 16) & 1);
    return (us)(r >> 16);
}
__device__ __forceinline__ float b2f(us u) {
    union { float f; unsigned u; } v; v.u = ((unsigned)u) << 16;
    return v.f;
}
// split: x ~= hi + lo  (17+ effective mantissa bits)
__device__ __forceinline__ void split2(float x, us& hi, us& lo) {
    hi = f2b(x);
    lo = f2b(x - b2f(hi));
}

__device__ __forceinline__ bf16x8 ld8(const us* p) {
    bf16x8 a;
    ((i64*)&a)[0] = *(const i64*)p;
    ((i64*)&a)[1] = *(const i64*)(p + 4);
    return a;
}

__device__ __forceinline__ void mfma3(f32x4& acc, bf16x8 ahi, bf16x8 alo,
                                      bf16x8 bhi, bf16x8 blo) {
    acc = __builtin_amdgcn_mfma_f32_16x16x32_bf16(ahi, bhi, acc, 0, 0, 0);
    acc = __builtin_amdgcn_mfma_f32_16x16x32_bf16(alo, bhi, acc, 0, 0, 0);
    acc = __builtin_amdgcn_mfma_f32_16x16x32_bf16(ahi, blo, acc, 0, 0, 0);
}

// ---------------- init: h (hi/lo bf16), coord/vel unpack ----------------
__global__ void k_init(const float* __restrict__ inp,
                       const float* __restrict__ emb_w,
                       const float* __restrict__ emb_b,
                       float* __restrict__ coord,
                       float* __restrict__ vel,
                       us* __restrict__ hbh, us* __restrict__ hbl) {
    int t = blockIdx.x * blockDim.x + threadIdx.x;   // n*64+f
    int n = t >> 6, f = t & 63;
    if (n >= N_NODES) return;
    float vx = inp[n*6+3], vy = inp[n*6+4], vz = inp[n*6+5];
    float sp = sqrtf(vx*vx + vy*vy + vz*vz);
    float hv = sp * emb_w[f] + emb_b[f];
    us hi, lo; split2(hv, hi, lo);
    hbh[t] = hi; hbl[t] = lo;
    if (f < 3) {
        coord[n*3+f] = inp[n*6+f];
        vel[n*3+f]   = inp[n*6+3+f];
    }
}

__global__ void k_count(const int* __restrict__ recv, float* __restrict__ cnt) {
    int t = blockIdx.x*blockDim.x + threadIdx.x;
    if (t < N_EDGES) atomicAdd(&cnt[recv[t]], 1.0f);
}

__global__ void k_invert(float* __restrict__ cnt) {
    int t = blockIdx.x*blockDim.x + threadIdx.x;
    if (t < N_NODES) cnt[t] = 1.0f / fmaxf(cnt[t], 1.0f);
}

// ---------------- weight prep: bf16 hi/lo transposed copies ----------------
__global__ void k_prepw(const float* __restrict__ ew1, const float* __restrict__ ew2,
                        const float* __restrict__ cw1,
                        us* __restrict__ w1th, us* __restrict__ w1tl,
                        us* __restrict__ w2th, us* __restrict__ w2tl,
                        us* __restrict__ cw1th, us* __restrict__ cw1tl) {
    int t = blockIdx.x*256 + threadIdx.x;   // 4 * 16384 total
    int l = t >> 14;
    int r = t & 16383;
    us hi, lo;
    if (r < 8192) {                          // n = r>>7, k = r&127
        int n = r >> 7, k = r & 127;
        split2(ew1[l*129*64 + k*64 + n], hi, lo);
        w1th[l*8192 + r] = hi; w1tl[l*8192 + r] = lo;
    } else if (r < 12288) {
        int rr = r - 8192; int n = rr >> 6, k = rr & 63;
        split2(ew2[l*4096 + k*64 + n], hi, lo);
        w2th[l*4096 + n*64 + k] = hi; w2tl[l*4096 + n*64 + k] = lo;
    } else {
        int rr = r - 12288; int n = rr >> 6, k = rr & 63;
        split2(cw1[l*4096 + k*64 + n], hi, lo);
        cw1th[l*4096 + n*64 + k] = hi; cw1tl[l*4096 + n*64 + k] = lo;
    }
}

// ---------------- fused MFMA edge kernel (split-bf16, ~fp32 precision) ----------------
// 256 threads = 4 waves; each wave owns 32 edges (2 M-tiles of 16).
__launch_bounds__(256)
__global__ void k_edge(const int* __restrict__ send, const int* __restrict__ recv,
                       const us* __restrict__ hbh, const us* __restrict__ hbl,
                       const float* __restrict__ coord,
                       const us* __restrict__ w1th, const us* __restrict__ w1tl,
                       const us* __restrict__ w2th, const us* __restrict__ w2tl,
                       const us* __restrict__ cw1th, const us* __restrict__ cw1tl,
                       const float* __restrict__ ew1,   // layer base (radial row fp32)
                       const float* __restrict__ eb1,
                       const float* __restrict__ eb2,
                       const float* __restrict__ cb1,
                       const float* __restrict__ cwo,
                       float* __restrict__ aggs, float* __restrict__ aggm) {
    __shared__ us tileh[4][32*TSTRIDE];
    __shared__ us tilel[4][32*TSTRIDE];

    const int tid  = threadIdx.x;
    const int wid  = tid >> 6;
    const int lane = tid & 63;
    const int q    = lane >> 4;
    const int l15  = lane & 15;
    const int ebase = blockIdx.x*128 + wid*32;

    const int s0 = send[ebase + l15],      r0 = recv[ebase + l15];
    const int s1 = send[ebase + 16 + l15], r1 = recv[ebase + 16 + l15];
    const float cdx0 = coord[s0*3+0] - coord[r0*3+0];
    const float cdy0 = coord[s0*3+1] - coord[r0*3+1];
    const float cdz0 = coord[s0*3+2] - coord[r0*3+2];
    const float cdx1 = coord[s1*3+0] - coord[r1*3+0];
    const float cdy1 = coord[s1*3+1] - coord[r1*3+1];
    const float cdz1 = coord[s1*3+2] - coord[r1*3+2];
    const float rad0 = cdx0*cdx0 + cdy0*cdy0 + cdz0*cdz0;
    const float rad1 = cdx1*cdx1 + cdy1*cdy1 + cdz1*cdz1;

    f32x4 acc[2][4];
    #pragma unroll
    for (int mu = 0; mu < 2; ++mu)
        #pragma unroll
        for (int t = 0; t < 4; ++t) acc[mu][t] = (f32x4){0.f,0.f,0.f,0.f};

    // ---- GEMM1: [32,128] @ [128,64]  (K=128 over h_send|h_recv) ----
    #pragma unroll
    for (int kc = 0; kc < 4; ++kc) {
        const int off = (kc & 1)*32 + q*8;
        const size_t o0 = (size_t)((kc < 2) ? s0 : r0)*64 + off;
        const size_t o1 = (size_t)((kc < 2) ? s1 : r1)*64 + off;
        bf16x8 a0h = ld8(hbh + o0), a0l = ld8(hbl + o0);
        bf16x8 a1h = ld8(hbh + o1), a1l = ld8(hbl + o1);
        #pragma unroll
        for (int t = 0; t < 4; ++t) {
            const int wo = (16*t + l15)*128 + kc*32 + q*8;
            bf16x8 bh = ld8(w1th + wo), bl = ld8(w1tl + wo);
            mfma3(acc[0][t], a0h, a0l, bh, bl);
            mfma3(acc[1][t], a1h, a1l, bh, bl);
        }
    }

    // radial column (fp32 exact) + bias
    float rs0[4], rs1[4];
    #pragma unroll
    for (int r = 0; r < 4; ++r) {
        rs0[r] = __shfl(rad0, 4*q + r);
        rs1[r] = __shfl(rad1, 4*q + r);
    }
    #pragma unroll
    for (int t = 0; t < 4; ++t) {
        const int col = 16*t + l15;
        const float wl = ew1[128*64 + col];
        const float bb = eb1[col];
        #pragma unroll
        for (int r = 0; r < 4; ++r) {
            acc[0][t][r] += rs0[r]*wl + bb;
            acc[1][t][r] += rs1[r]*wl + bb;
        }
    }

    // t1 = silu -> LDS hi/lo tiles (C-layout -> A-layout round trip)
    us* Th = tileh[wid];
    us* Tl = tilel[wid];
    #pragma unroll
    for (int mu = 0; mu < 2; ++mu)
        #pragma unroll
        for (int t = 0; t < 4; ++t)
            #pragma unroll
            for (int r = 0; r < 4; ++r) {
                us hi, lo; split2(silu_f(acc[mu][t][r]), hi, lo);
                const int ti = (mu*16 + 4*q + r)*TSTRIDE + 16*t + l15;
                Th[ti] = hi; Tl[ti] = lo;
            }
    __syncthreads();

    // ---- GEMM2: t1 @ W2 ----
    #pragma unroll
    for (int mu = 0; mu < 2; ++mu)
        #pragma unroll
        for (int t = 0; t < 4; ++t) acc[mu][t] = (f32x4){0.f,0.f,0.f,0.f};
    #pragma unroll
    for (int kc = 0; kc < 2; ++kc) {
        const int t0 = l15*TSTRIDE + kc*32 + q*8;
        const int t1i = (16+l15)*TSTRIDE + kc*32 + q*8;
        bf16x8 a0h = ld8(Th + t0),  a0l = ld8(Tl + t0);
        bf16x8 a1h = ld8(Th + t1i), a1l = ld8(Tl + t1i);
        #pragma unroll
        for (int t = 0; t < 4; ++t) {
            const int wo = (16*t + l15)*64 + kc*32 + q*8;
            bf16x8 bh = ld8(w2th + wo), bl = ld8(w2tl + wo);
            mfma3(acc[0][t], a0h, a0l, bh, bl);
            mfma3(acc[1][t], a1h, a1l, bh, bl);
        }
    }

    // ef = silu(acc + b2) -> regs (fp32, for scatter) and LDS hi/lo (for GEMM3)
    float ef[2][4][4];
    #pragma unroll
    for (int t = 0; t < 4; ++t) {
        const float bb = eb2[16*t + l15];
        #pragma unroll
        for (int mu = 0; mu < 2; ++mu)
            #pragma unroll
            for (int r = 0; r < 4; ++r)
                ef[mu][t][r] = silu_f(acc[mu][t][r] + bb);
    }
    __syncthreads();
    #pragma unroll
    for (int mu = 0; mu < 2; ++mu)
        #pragma unroll
        for (int t = 0; t < 4; ++t)
            #pragma unroll
            for (int r = 0; r < 4; ++r) {
                us hi, lo; split2(ef[mu][t][r], hi, lo);
                const int ti = (mu*16 + 4*q + r)*TSTRIDE + 16*t + l15;
                Th[ti] = hi; Tl[ti] = lo;
            }
    __syncthreads();

    // ---- GEMM3: ef @ CW1 ----
    #pragma unroll
    for (int mu = 0; mu < 2; ++mu)
        #pragma unroll
        for (int t = 0; t < 4; ++t) acc[mu][t] = (f32x4){0.f,0.f,0.f,0.f};
    #pragma unroll
    for (int kc = 0; kc < 2; ++kc) {
        const int t0 = l15*TSTRIDE + kc*32 + q*8;
        const int t1i = (16+l15)*TSTRIDE + kc*32 + q*8;
        bf16x8 a0h = ld8(Th + t0),  a0l = ld8(Tl + t0);
        bf16x8 a1h = ld8(Th + t1i), a1l = ld8(Tl + t1i);
        #pragma unroll
        for (int t = 0; t < 4; ++t) {
            const int wo = (16*t + l15)*64 + kc*32 + q*8;
            bf16x8 bh = ld8(cw1th + wo), bl = ld8(cw1tl + wo);
            mfma3(acc[0][t], a0h, a0l, bh, bl);
            mfma3(acc[1][t], a1h, a1l, bh, bl);
        }
    }

    // ---- GEMM4: cm = silu(acc + cb1) @ CWo, reduce across l15 within quad ----
    float cm0[4] = {0.f,0.f,0.f,0.f}, cm1[4] = {0.f,0.f,0.f,0.f};
    #pragma unroll
    for (int t = 0; t < 4; ++t) {
        const int col = 16*t + l15;
        const float cb = cb1[col];
        const float co = cwo[col];
        #pragma unroll
        for (int r = 0; r < 4; ++r) {
            cm0[r] += silu_f(acc[0][t][r] + cb) * co;
            cm1[r] += silu_f(acc[1][t][r] + cb) * co;
        }
    }
    #pragma unroll
    for (int m = 1; m <= 8; m <<= 1)
        #pragma unroll
        for (int r = 0; r < 4; ++r) {
            cm0[r] += __shfl_xor(cm0[r], m);
            cm1[r] += __shfl_xor(cm1[r], m);
        }

    // ---- scatter: aggm (trans mean numerator) + aggs (ef sum) ----
    int re0s[4], re1s[4];
    #pragma unroll
    for (int r = 0; r < 4; ++r) {
        re0s[r] = __shfl(r0, 4*q + r);
        re1s[r] = __shfl(r1, 4*q + r);
    }
    #pragma unroll
    for (int mu = 0; mu < 2; ++mu)
        #pragma unroll
        for (int r = 0; r < 4; ++r) {
            float cx = __shfl(mu ? cdx1 : cdx0, 4*q + r);
            float cy = __shfl(mu ? cdy1 : cdy0, 4*q + r);
            float cz = __shfl(mu ? cdz1 : cdz0, 4*q + r);
            float cmv = mu ? cm1[r] : cm0[r];
            int   ree = mu ? re1s[r] : re0s[r];
            if (l15 < 3) {
                float sel = (l15 == 0) ? cx : (l15 == 1) ? cy : cz;
                float tv  = fminf(fmaxf(sel*cmv, -100.f), 100.f);
                atomicAdd(&aggm[ree*3 + l15], tv);
            }
        }
    #pragma unroll
    for (int mu = 0; mu < 2; ++mu)
        #pragma unroll
        for (int r = 0; r < 4; ++r) {
            const int ree = mu ? re1s[r] : re0s[r];
            #pragma unroll
            for (int t = 0; t < 4; ++t)
                atomicAdd(&aggs[ree*64 + 16*t + l15], ef[mu][t][r]);
        }
}

// ---------------- node kernel (fp32 math; h stored as hi/lo bf16 pair) ----------------
__launch_bounds__(256, 4)
__global__ void k_node(const float* __restrict__ aggs, const float* __restrict__ aggm,
                       const float* __restrict__ icnt,
                       const float* __restrict__ VW1, const float* __restrict__ vb1,
                       const float* __restrict__ VW2, const float* __restrict__ vb2,
                       const float* __restrict__ NW1, const float* __restrict__ nb1,
                       const float* __restrict__ NW2, const float* __restrict__ nb2,
                       float* __restrict__ coord, float* __restrict__ vel,
                       us* __restrict__ hbh, us* __restrict__ hbl) {
    __shared__ float hs[4][64], as[4][64], tt[4][64];
    const int tid = threadIdx.x;
    const int nn = tid >> 6, f = tid & 63;
    const int n = blockIdx.x*4 + nn;
    float hv = b2f(hbh[n*64+f]) + b2f(hbl[n*64+f]);
    hs[nn][f] = hv;
    as[nn][f] = aggs[n*64+f];
    __syncthreads();

    float a1 = vb1[f];
    for (int k = 0; k < 64; ++k) a1 += hs[nn][k] * VW1[k*64+f];
    float p = silu_f(a1) * VW2[f];
    #pragma unroll
    for (int o = 32; o > 0; o >>= 1) p += __shfl_down(p, o);
    float vgate = __shfl(p, 0) + vb2[0];

    if (f < 3) {
        float nv = aggm[n*3+f]*icnt[n] + vgate*vel[n*3+f];
        vel[n*3+f] = nv;
        coord[n*3+f] += nv;
    }

    float b = nb1[f];
    for (int k = 0; k < 64; ++k) b += hs[nn][k]*NW1[k*64+f];
    for (int k = 0; k < 64; ++k) b += as[nn][k]*NW1[(64+k)*64+f];
    __syncthreads();
    tt[nn][f] = silu_f(b);
    __syncthreads();
    float o = nb2[f] + hv;
    for (int k = 0; k < 64; ++k) o += tt[nn][k]*NW2[k*64+f];
    us hi, lo; split2(o, hi, lo);
    hbh[n*64+f] = hi; hbl[n*64+f] = lo;
}

__global__ void k_out(const float* __restrict__ coord, const float* __restrict__ vel,
                      float* __restrict__ out) {
    int t = blockIdx.x*blockDim.x + threadIdx.x;
    if (t >= N_NODES*6) return;
    int n = t/6, c = t%6;
    out[t] = (c < 3) ? coord[n*3+c] : vel[n*3+(c-3)];
}

extern "C" void kernel_launch(void* const* d_in, const int* in_sizes, int n_in,
                              void* d_out, int out_size, void* d_ws, size_t ws_size,
                              hipStream_t stream) {
    const float* inp   = (const float*)d_in[0];
    const int*   send  = (const int*)d_in[2];
    const int*   recv  = (const int*)d_in[3];
    const float* emb_w = (const float*)d_in[4];
    const float* emb_b = (const float*)d_in[5];
    const float* ew1   = (const float*)d_in[6];
    const float* eb1   = (const float*)d_in[7];
    const float* ew2   = (const float*)d_in[8];
    const float* eb2   = (const float*)d_in[9];
    const float* nw1   = (const float*)d_in[10];
    const float* nb1   = (const float*)d_in[11];
    const float* nw2   = (const float*)d_in[12];
    const float* nb2   = (const float*)d_in[13];
    const float* cw1   = (const float*)d_in[14];
    const float* cb1   = (const float*)d_in[15];
    const float* cwo   = (const float*)d_in[16];
    const float* vw1   = (const float*)d_in[17];
    const float* vb1   = (const float*)d_in[18];
    const float* vw2   = (const float*)d_in[19];
    const float* vb2   = (const float*)d_in[20];

    // ws layout (total ~11.3 MB, within the R2-proven envelope)
    float* ws    = (float*)d_ws;
    float* coord = ws;                        // N*3
    float* vel   = coord + N_NODES*3;         // N*3
    float* aggs  = vel + N_NODES*3;           // N*64
    float* aggm  = aggs + N_NODES*64;         // N*3 (contiguous with aggs)
    float* icnt  = aggm + N_NODES*3;          // N
    us* hbh   = (us*)(icnt + N_NODES);        // N*64
    us* hbl   = hbh + N_NODES*64;             // N*64
    us* w1th  = hbl + N_NODES*64;             // 4*8192
    us* w1tl  = w1th + 4*8192;
    us* w2th  = w1tl + 4*8192;                // 4*4096
    us* w2tl  = w2th + 4*4096;
    us* cw1th = w2tl + 4*4096;
    us* cw1tl = cw1th + 4*4096;

    hipMemsetAsync(icnt, 0, N_NODES*sizeof(float), stream);
    k_init<<<(N_NODES*64)/256, 256, 0, stream>>>(inp, emb_w, emb_b, coord, vel, hbh, hbl);
    k_count<<<(N_EDGES+255)/256, 256, 0, stream>>>(recv, icnt);
    k_invert<<<(N_NODES+255)/256, 256, 0, stream>>>(icnt);
    k_prepw<<<256, 256, 0, stream>>>(ew1, ew2, cw1, w1th, w1tl, w2th, w2tl, cw1th, cw1tl);

    for (int l = 0; l < NLAYERS; ++l) {
        hipMemsetAsync(aggs, 0, (size_t)N_NODES*67*sizeof(float), stream);
        k_edge<<<N_EDGES/128, 256, 0, stream>>>(send, recv, hbh, hbl, coord,
            w1th + l*8192, w1tl + l*8192,
            w2th + l*4096, w2tl + l*4096,
            cw1th + l*4096, cw1tl + l*4096,
            ew1 + (size_t)l*129*64, eb1 + l*64, eb2 + l*64,
            cb1 + l*64, cwo + l*64,
            aggs, aggm);
        k_node<<<N_NODES/4, 256, 0, stream>>>(aggs, aggm, icnt,
            vw1 + (size_t)l*64*64, vb1 + l*64, vw2 + l*64, vb2 + l,
            nw1 + (size_t)l*128*64, nb1 + l*64,
            nw2 + (size_t)l*64*64,  nb2 + l*64,
            coord, vel, hbh, hbl);
    }
    k_out<<<(N_NODES*6+255)/256, 256, 0, stream>>>(coord, vel, (float*)d_out);
}